// Round 15
// baseline (171.670 us; speedup 1.0000x reference)
//
#include <hip/hip_runtime.h>
#include <stdint.h>

#define D_MODEL 512
#define INNER   1024
#define NCAT    4096
#define BATCH   8
#define SEQ     2048
#define ROWS    (BATCH*SEQ)
#define LN_EPS  1e-5f
#define CHUNK   64
#define NCHUNK  (SEQ/CHUNK)

typedef unsigned short u16;
typedef unsigned int   u32;
typedef __attribute__((ext_vector_type(8))) short bf16x8;
typedef __attribute__((ext_vector_type(4))) float f32x4;

__device__ __forceinline__ u16 f2bf(float f) {
  u32 u = __builtin_bit_cast(u32, f);
  return (u16)((u + 0x7FFFu + ((u >> 16) & 1u)) >> 16);
}
__device__ __forceinline__ float bf2f(u32 lo) {
  return __builtin_bit_cast(float, lo << 16);
}
__device__ __forceinline__ float sigf(float x){ return 1.f/(1.f+__expf(-x)); }

__device__ __forceinline__ void glds16(const void* g, void* l) {
  __builtin_amdgcn_global_load_lds((const __attribute__((address_space(1))) void*)g,
                                   (__attribute__((address_space(3))) void*)l, 16, 0, 0);
}

#define MFMA16(a,b,c) __builtin_amdgcn_mfma_f32_16x16x32_bf16((a),(b),(c),0,0,0)

// ---------------- prep: LayerNorm (blocks 0..4095) + weight cvt/reorder (4096..5119) ----
__global__ __launch_bounds__(256) void prep_kernel(const float* __restrict__ x,
    const float* __restrict__ lw, const float* __restrict__ lb,
    const float* __restrict__ ipw, const float* __restrict__ dw,
    const float* __restrict__ opw, const float* __restrict__ ipb,
    const float* __restrict__ db, u16* __restrict__ xn,
    u16* __restrict__ wcat, u16* __restrict__ wout, float* __restrict__ bcat) {
  const int bid = blockIdx.x;
  if (bid < ROWS/4) {
    const int row  = bid * 4 + (threadIdx.x >> 6);
    const int lane = threadIdx.x & 63;
    const float4* xr = (const float4*)(x + (size_t)row * D_MODEL);
    float4 v0 = xr[lane*2], v1 = xr[lane*2+1];
    float s  = v0.x+v0.y+v0.z+v0.w + v1.x+v1.y+v1.z+v1.w;
    float s2 = v0.x*v0.x+v0.y*v0.y+v0.z*v0.z+v0.w*v0.w
             + v1.x*v1.x+v1.y*v1.y+v1.z*v1.z+v1.w*v1.w;
    #pragma unroll
    for (int o=32;o;o>>=1){ s += __shfl_xor(s,o); s2 += __shfl_xor(s2,o); }
    const float mu = s * (1.f/D_MODEL);
    const float rs = rsqrtf(s2*(1.f/D_MODEL) - mu*mu + LN_EPS);
    const float4* wv = (const float4*)lw; const float4* bv = (const float4*)lb;
    float4 w0 = wv[lane*2], w1 = wv[lane*2+1];
    float4 b0 = bv[lane*2], b1 = bv[lane*2+1];
    u32 p0 = (u32)f2bf((v0.x-mu)*rs*w0.x+b0.x) | ((u32)f2bf((v0.y-mu)*rs*w0.y+b0.y)<<16);
    u32 p1 = (u32)f2bf((v0.z-mu)*rs*w0.z+b0.z) | ((u32)f2bf((v0.w-mu)*rs*w0.w+b0.w)<<16);
    u32 p2 = (u32)f2bf((v1.x-mu)*rs*w1.x+b1.x) | ((u32)f2bf((v1.y-mu)*rs*w1.y+b1.y)<<16);
    u32 p3 = (u32)f2bf((v1.z-mu)*rs*w1.z+b1.z) | ((u32)f2bf((v1.w-mu)*rs*w1.w+b1.w)<<16);
    ((uint4*)(xn + (size_t)row * D_MODEL))[lane] = make_uint4(p0,p1,p2,p3);
  } else {
    const int i = (bid - ROWS/4)*256 + threadIdx.x;
    const int NW1 = NCAT*D_MODEL, NW2 = D_MODEL*INNER, STR = 1024*256;
    for (int idx = i; idx < NW1; idx += STR) {
      const int r = idx >> 9, c = idx & 511;
      float v;
      if (r < 2048) v = ipw[idx];
      else {
        const int rr = r - 2048;
        v = (rr & 1) ? dw[(size_t)(rr>>1)*D_MODEL + c]
                     : ipw[(size_t)(2048 + (rr>>1))*D_MODEL + c];
      }
      wcat[idx] = f2bf(v);
    }
    for (int idx = i; idx < NW2; idx += STR) wout[idx] = f2bf(opw[idx]);
    if (i < NCAT) {
      float b;
      if (i < 2048) b = ipb[i];
      else { const int rr = i - 2048; b = (rr & 1) ? db[rr>>1] : ipb[2048 + (rr>>1)]; }
      bcat[i] = b;
    }
  }
}

// ---------------- block swizzle: XCD-chunked + L2-sized (GMxGN) groups ----------------
__device__ __forceinline__ void sched_blk(int nbm, int nbn, int GM, int GN,
                                          int& bM, int& bN) {
  const int nwg = nbm * nbn;
  const int bid = blockIdx.x;
  const int cpx = nwg >> 3;
  const int swz = (bid & 7) * cpx + (bid >> 3);   // contiguous chunk per XCD
  const int gsz = GM * GN;
  const int g   = swz / gsz, loc = swz - g * gsz;
  const int ngn = nbn / GN;
  const int gm  = g / ngn,  gn  = g - gm * ngn;
  bM = gm * GM + (loc % GM);
  bN = gn * GN + (loc / GM);
}

// ================= GEMM1: 256x256 tile, BK=32, 8 waves (2Mx4N, 128x64 each) =====
// r12 measured-best mainloop (frozen). d-region epilogue fuses scan pass 1.
__global__ __launch_bounds__(512, 2) void gemm1_kernel(const u16* __restrict__ A,
    const u16* __restrict__ Bm, const float* __restrict__ bcat,
    const float* __restrict__ sm, u16* __restrict__ proj, u16* __restrict__ gate,
    u16* __restrict__ dbuf, float* __restrict__ cS) {
  extern __shared__ u16 lds[];                     // 3 x 16384 u16 (A 8192 | B 8192)
  const int tid = threadIdx.x;
  int bM, bN; sched_blk(ROWS/256, NCAT/256, 8, 4, bM, bN);

  const u16* gA0; const u16* gA1; const u16* gB0; const u16* gB1;
  {
    const int p0 = tid,        q0 = p0>>3, t0 = (p0&7) ^ (q0&7);
    const int p1 = 512 + tid,  q1 = p1>>3, t1 = (p1&7) ^ (q1&7);
    const int rA0 = q0*2 + (t0>>2), sA0 = t0&3;
    const int rA1 = q1*2 + (t1>>2), sA1 = t1&3;
    gA0 = A + (size_t)(bM*256 + rA0)*D_MODEL + sA0*8;
    gA1 = A + (size_t)(bM*256 + rA1)*D_MODEL + sA1*8;
    const int c0 = (rA0 & ~63) + ((rA0&15)*4) + ((rA0>>4)&3);
    const int c1 = (rA1 & ~63) + ((rA1&15)*4) + ((rA1>>4)&3);
    gB0 = Bm + (size_t)(bN*256 + c0)*D_MODEL + sA0*8;
    gB1 = Bm + (size_t)(bN*256 + c1)*D_MODEL + sA1*8;
  }

#define STAGE1(KOFF, BUFO) do { \
    glds16(gA0 + (KOFF), lds + (BUFO) + tid*8); \
    glds16(gA1 + (KOFF), lds + (BUFO) + 4096 + tid*8); \
    glds16(gB0 + (KOFF), lds + (BUFO) + 8192 + tid*8); \
    glds16(gB1 + (KOFF), lds + (BUFO) + 12288 + tid*8); } while(0)

  const int lane = tid & 63, wid = tid >> 6;
  const int wm = wid >> 2, wn = wid & 3;          // 2M x 4N waves
  const int rl = lane & 15;
  const int e  = (((lane&1)<<2) + (lane>>4)) ^ (rl>>1);
  const int aoff = wm*4096 + (rl>>1)*64 + e*8;
  const int boff = 8192 + wn*2048 + (rl>>1)*64 + e*8;

  f32x4 acc[8][4];
  #pragma unroll
  for (int m=0;m<8;m++)
    #pragma unroll
    for (int n=0;n<4;n++) acc[m][n] = (f32x4){0.f,0.f,0.f,0.f};

  STAGE1(0, 0);
  STAGE1(32, 16384);
  asm volatile("s_waitcnt vmcnt(4)" ::: "memory");
  __builtin_amdgcn_s_barrier();
  __builtin_amdgcn_sched_barrier(0);

  int cur = 0, stg = 32768;
  for (int kt = 0; kt < 16; ++kt) {
    bf16x8 af[8], bfr[4];
    #pragma unroll
    for (int m=0;m<8;m++) af[m]  = *(const bf16x8*)&lds[cur + aoff + m*512];
    #pragma unroll
    for (int n=0;n<4;n++) bfr[n] = *(const bf16x8*)&lds[cur + boff + n*512];
    if (kt + 2 < 16) STAGE1((kt+2)*32, stg);
    #pragma unroll
    for (int m=0;m<8;m++)
      #pragma unroll
      for (int n=0;n<4;n++)
        acc[m][n] = MFMA16(af[m], bfr[n], acc[m][n]);
    if (kt + 2 < 16) { asm volatile("s_waitcnt vmcnt(4)" ::: "memory"); }
    else             { asm volatile("s_waitcnt vmcnt(0)" ::: "memory"); }
    __builtin_amdgcn_s_barrier();
    __builtin_amdgcn_sched_barrier(0);
    cur += 16384; if (cur == 49152) cur = 0;
    stg += 16384; if (stg == 49152) stg = 0;
  }
#undef STAGE1

  const int colb = bN*256 + wn*64 + rl*4;
  const float4 b4 = *(const float4*)&bcat[colb];
  const float* bp = (const float*)&b4;
  if (colb < 2048) {
    u16* outp = (colb < 1024) ? proj : gate;
    const int lcolb = colb & (INNER-1);
    #pragma unroll
    for (int m=0;m<8;m++) {
      const int row0 = bM*256 + wm*128 + m*16 + ((lane>>4)<<2);
      #pragma unroll
      for (int r=0;r<4;r++) {
        float a4[4];
        #pragma unroll
        for (int n=0;n<4;n++) {
          float v = acc[m][n][r] + bp[n];
          a4[n] = (colb < 1024) ? v * sigf(v) : sigf(v);
        }
        u32 lo = (u32)f2bf(a4[0]) | ((u32)f2bf(a4[1])<<16);
        u32 hi = (u32)f2bf(a4[2]) | ((u32)f2bf(a4[3])<<16);
        *(uint2*)&outp[(size_t)(row0+r)*INNER + lcolb] = make_uint2(lo, hi);
      }
    }
  } else {
    const int ch0 = (colb - 2048) >> 1;
    const int g = lane >> 4;
    const float A0 = sigf(sm[ch0]), A1 = sigf(sm[ch0+1]);
    const float A0_2 = A0*A0,   A1_2 = A1*A1;
    const float A0_4 = A0_2*A0_2, A1_4 = A1_2*A1_2;
    const float A0_8 = A0_4*A0_4, A1_8 = A1_4*A1_4;
    const float A0_16 = A0_8*A0_8, A1_16 = A1_8*A1_8;
    float S0a = 0.f, S0b = 0.f, S1a = 0.f, S1b = 0.f;
    #pragma unroll
    for (int m=0;m<8;m++) {
      const int row0 = bM*256 + wm*128 + m*16 + (g<<2);
      float sg0 = 0.f, sg1 = 0.f;
      #pragma unroll
      for (int r=0;r<4;r++) {
        const float v0 = acc[m][0][r] + bp[0];
        const float v1 = acc[m][1][r] + bp[1];
        const float v2 = acc[m][2][r] + bp[2];
        const float v3 = acc[m][3][r] + bp[3];
        const float d0 = (2.f*sigf(2.f*v0) - 1.f) * fmaxf(sigf(v1), 1e-4f);
        const float d1 = (2.f*sigf(2.f*v2) - 1.f) * fmaxf(sigf(v3), 1e-4f);
        *(u32*)&dbuf[(size_t)(row0+r)*INNER + ch0] = (u32)f2bf(d0) | ((u32)f2bf(d1)<<16);
        sg0 = A0*sg0 + d0;
        sg1 = A1*sg1 + d1;
      }
      float p0 = __shfl_xor(sg0, 16), p1 = __shfl_xor(sg1, 16);
      float e0 = (g & 1) ? (sg0 + A0_4*p0) : (p0 + A0_4*sg0);
      float e1 = (g & 1) ? (sg1 + A1_4*p1) : (p1 + A1_4*sg1);
      float q0 = __shfl_xor(e0, 32), q1 = __shfl_xor(e1, 32);
      float s16_0 = (g & 2) ? (e0 + A0_8*q0) : (q0 + A0_8*e0);
      float s16_1 = (g & 2) ? (e1 + A1_8*q1) : (q1 + A1_8*e1);
      if (m < 4) { S0a = A0_16*S0a + s16_0; S1a = A1_16*S1a + s16_1; }
      else       { S0b = A0_16*S0b + s16_0; S1b = A1_16*S1b + s16_1; }
    }
    if (g == 0) {
      const int b = bM >> 3;
      const int chunk0 = (bM & 7)*4 + wm*2;
      const size_t o0 = ((size_t)b*NCHUNK + chunk0    )*INNER + ch0;
      const size_t o1 = ((size_t)b*NCHUNK + chunk0 + 1)*INNER + ch0;
      *(float2*)&cS[o0] = make_float2(S0a, S1a);
      *(float2*)&cS[o1] = make_float2(S0b, S1b);
    }
  }
}

// ======== fused scan3+GEMM2: block=(b,chunk); phase A builds z[64][1024] in LDS
// (XOR-swizzled: 16B-chunk index ^= (row&7)); phase B (barrier-free) computes
// out rows t0..t0+63 = z @ wout^T + bias + residual. wout streamed from global
// (1MB, L2-resident per XCD). ========
__global__ __launch_bounds__(512, 1) void fused_sg2_kernel(const u16* __restrict__ proj,
    const u16* __restrict__ gate, const u16* __restrict__ d,
    const float* __restrict__ cS, const float* __restrict__ sm,
    const float* __restrict__ cw, const float* __restrict__ cb,
    const float* __restrict__ sk, const u16* __restrict__ wout,
    const float* __restrict__ ob, const float* __restrict__ resid,
    float* __restrict__ out) {
  extern __shared__ u16 zl[];                      // 64 x 1024 u16 = 128KB
  const int tid = threadIdx.x;
  const int b = blockIdx.x >> 5, ch = blockIdx.x & 31;
  const int t0 = ch*CHUNK;

  // ---------------- phase A: scan + conv + gate -> z in LDS ----------------
  {
    const int c0 = tid*2;
    const float a0 = sigf(sm[c0]), a1 = sigf(sm[c0+1]);
    const float cb0 = cb[c0], cb1 = cb[c0+1];
    const float sk0 = sk[c0], sk1 = sk[c0+1];
    const float w00=cw[c0*4+0], w01=cw[c0*4+1], w02=cw[c0*4+2], w03=cw[c0*4+3];
    const float w10=cw[c0*4+4], w11=cw[c0*4+5], w12=cw[c0*4+6], w13=cw[c0*4+7];
    float A0 = a0, A1 = a1;
    #pragma unroll
    for (int i=0;i<6;i++){ A0*=A0; A1*=A1; }       // a^64
    float s0 = 0.f, s1 = 0.f;
    for (int j = 0; j < ch; ++j) {
      const size_t oj = ((size_t)b*NCHUNK + j)*INNER + c0;
      const float2 cv = *(const float2*)&cS[oj];
      s0 = A0*s0 + cv.x;
      s1 = A1*s1 + cv.y;
    }
    const size_t rowb = (size_t)b*SEQ*INNER + c0;
    float pa0=0,pb0=0,pc0=0, pa1=0,pb1=0,pc1=0;
    if (ch > 0) {
      u32 u3 = *(const u32*)(proj + rowb + (size_t)(t0-3)*INNER);
      u32 u2 = *(const u32*)(proj + rowb + (size_t)(t0-2)*INNER);
      u32 u1 = *(const u32*)(proj + rowb + (size_t)(t0-1)*INNER);
      pa0 = bf2f(u3&0xffffu); pa1 = bf2f(u3>>16);
      pb0 = bf2f(u2&0xffffu); pb1 = bf2f(u2>>16);
      pc0 = bf2f(u1&0xffffu); pc1 = bf2f(u1>>16);
    }
    // z LDS index: row t, channel c: u16 idx = t*1024 + (((c>>3)^(t&7))<<3) + (c&7)
    const int ck = c0 >> 3, wi = c0 & 7;           // c0 even -> wi even
    size_t base = rowb + (size_t)t0*INNER;
    for (int t=0;t<CHUNK;t++) {
      u32 pu = *(const u32*)(proj + base);
      const float pd0 = bf2f(pu&0xffffu), pd1 = bf2f(pu>>16);
      const float co0 = w00*pa0 + w01*pb0 + w02*pc0 + w03*pd0 + cb0;
      const float co1 = w10*pa1 + w11*pb1 + w12*pc1 + w13*pd1 + cb1;
      pa0=pb0; pb0=pc0; pc0=pd0;  pa1=pb1; pb1=pc1; pc1=pd1;
      u32 du = *(const u32*)(d + base);
      s0 = a0*s0 + bf2f(du&0xffffu);
      s1 = a1*s1 + bf2f(du>>16);
      u32 gu = *(const u32*)(gate + base);
      const float z0 = (s0 + sk0*co0)*bf2f(gu&0xffffu);
      const float z1 = (s1 + sk1*co1)*bf2f(gu>>16);
      const int zi = t*1024 + (((ck ^ (t&7)) << 3) | wi);
      *(u32*)&zl[zi] = (u32)f2bf(z0) | ((u32)f2bf(z1)<<16);
      base += INNER;
    }
  }
  __syncthreads();

  // ---------------- phase B: 64x1024 @ wout^T (barrier-free) ----------------
  const int lane = tid & 63, w8 = tid >> 6;
  const int nb0 = w8*64;                            // output col block (of 512)
  const int r15 = lane & 15, k8 = lane >> 4;        // frag row sel / k-octet
  f32x4 acc[4][4];
  #pragma unroll
  for (int m=0;m<4;m++)
    #pragma unroll
    for (int n=0;n<4;n++) acc[m][n] = (f32x4){0.f,0.f,0.f,0.f};

  // B source base: wout[(nb0 + n*16 + r15)][kk*32 + k8*8]
  const u16* gB = wout + (size_t)(nb0 + r15)*INNER + k8*8;

  #pragma unroll 4
  for (int kk = 0; kk < 32; ++kk) {
    bf16x8 bfr[4];
    #pragma unroll
    for (int n=0;n<4;n++)
      bfr[n] = *(const bf16x8*)(gB + (size_t)(n*16)*INNER + kk*32);
    bf16x8 afr[4];
    #pragma unroll
    for (int m=0;m<4;m++) {
      const int row = m*16 + r15;
      const int lchunk = kk*4 + k8;
      afr[m] = *(const bf16x8*)&zl[row*1024 + ((lchunk ^ (row&7)) << 3)];
    }
    #pragma unroll
    for (int m=0;m<4;m++)
      #pragma unroll
      for (int n=0;n<4;n++)
        acc[m][n] = MFMA16(afr[m], bfr[n], acc[m][n]);
  }

  // ---- epilogue: bias + residual, fp32 out ----
  #pragma unroll
  for (int n=0;n<4;n++) {
    const int col = nb0 + n*16 + r15;
    const float bias = ob[col];
    #pragma unroll
    for (int m=0;m<4;m++) {
      const int grow = b*SEQ + t0 + m*16 + (k8<<2);
      #pragma unroll
      for (int r=0;r<4;r++) {
        const size_t idx = (size_t)(grow + r)*D_MODEL + col;
        out[idx] = acc[m][n][r] + bias + resid[idx];
      }
    }
  }
}

extern "C" void kernel_launch(void* const* d_in, const int* in_sizes, int n_in,
                              void* d_out, int out_size, void* d_ws, size_t ws_size,
                              hipStream_t stream) {
  const float* x    = (const float*)d_in[0];
  const float* ln_w = (const float*)d_in[1];
  const float* ln_b = (const float*)d_in[2];
  const float* ipw  = (const float*)d_in[3];
  const float* ipb  = (const float*)d_in[4];
  const float* cw   = (const float*)d_in[5];
  const float* cb   = (const float*)d_in[6];
  const float* dw   = (const float*)d_in[7];
  const float* db   = (const float*)d_in[8];
  const float* sm   = (const float*)d_in[9];
  const float* sk   = (const float*)d_in[10];
  const float* opw  = (const float*)d_in[11];
  const float* opb  = (const float*)d_in[12];
  float* out = (float*)d_out;

  uint8_t* w = (uint8_t*)d_ws;
  u16* xn    = (u16*)w;  w += (size_t)ROWS*D_MODEL*2;
  u16* wcat  = (u16*)w;  w += (size_t)NCAT*D_MODEL*2;
  u16* wout  = (u16*)w;  w += (size_t)D_MODEL*INNER*2;
  u16* proj  = (u16*)w;  w += (size_t)ROWS*INNER*2;
  u16* gate  = (u16*)w;  w += (size_t)ROWS*INNER*2;
  u16* dbuf  = (u16*)w;  w += (size_t)ROWS*INNER*2;
  float* cS    = (float*)w; w += (size_t)BATCH*NCHUNK*INNER*4;
  float* bcat  = (float*)w; w += (size_t)NCAT*4;

  prep_kernel<<<ROWS/4 + 1024, 256, 0, stream>>>(x, ln_w, ln_b, ipw, dw, opw, ipb, db,
                                                 xn, wcat, wout, bcat);
  gemm1_kernel<<<(ROWS/256)*(NCAT/256), 512, 98304, stream>>>(xn, wcat, bcat, sm, proj, gate, dbuf, cS);
  fused_sg2_kernel<<<BATCH*NCHUNK, 512, 131072, stream>>>(proj, gate, dbuf, cS, sm, cw, cb,
                                                          sk, wout, opb, x, out);
}

// Round 16
// 165.413 us; speedup vs baseline: 1.0378x; 1.0378x over previous
//
#include <hip/hip_runtime.h>
#include <stdint.h>

#define D_MODEL 512
#define INNER   1024
#define NCAT    4096
#define BATCH   8
#define SEQ     2048
#define ROWS    (BATCH*SEQ)
#define LN_EPS  1e-5f
#define CHUNK   64
#define NCHUNK  (SEQ/CHUNK)

typedef unsigned short u16;
typedef unsigned int   u32;
typedef __attribute__((ext_vector_type(8))) short bf16x8;
typedef __attribute__((ext_vector_type(4))) float f32x4;

__device__ __forceinline__ u16 f2bf(float f) {
  u32 u = __builtin_bit_cast(u32, f);
  return (u16)((u + 0x7FFFu + ((u >> 16) & 1u)) >> 16);
}
__device__ __forceinline__ float bf2f(u32 lo) {
  return __builtin_bit_cast(float, lo << 16);
}
__device__ __forceinline__ float sigf(float x){ return 1.f/(1.f+__expf(-x)); }

__device__ __forceinline__ void glds16(const void* g, void* l) {
  __builtin_amdgcn_global_load_lds((const __attribute__((address_space(1))) void*)g,
                                   (__attribute__((address_space(3))) void*)l, 16, 0, 0);
}

#define MFMA16(a,b,c) __builtin_amdgcn_mfma_f32_16x16x32_bf16((a),(b),(c),0,0,0)

// ---------------- prep: LayerNorm (blocks 0..4095) + weight cvt/reorder (4096..5119) ----
__global__ __launch_bounds__(256) void prep_kernel(const float* __restrict__ x,
    const float* __restrict__ lw, const float* __restrict__ lb,
    const float* __restrict__ ipw, const float* __restrict__ dw,
    const float* __restrict__ opw, const float* __restrict__ ipb,
    const float* __restrict__ db, u16* __restrict__ xn,
    u16* __restrict__ wcat, u16* __restrict__ wout, float* __restrict__ bcat) {
  const int bid = blockIdx.x;
  if (bid < ROWS/4) {
    const int row  = bid * 4 + (threadIdx.x >> 6);
    const int lane = threadIdx.x & 63;
    const float4* xr = (const float4*)(x + (size_t)row * D_MODEL);
    float4 v0 = xr[lane*2], v1 = xr[lane*2+1];
    float s  = v0.x+v0.y+v0.z+v0.w + v1.x+v1.y+v1.z+v1.w;
    float s2 = v0.x*v0.x+v0.y*v0.y+v0.z*v0.z+v0.w*v0.w
             + v1.x*v1.x+v1.y*v1.y+v1.z*v1.z+v1.w*v1.w;
    #pragma unroll
    for (int o=32;o;o>>=1){ s += __shfl_xor(s,o); s2 += __shfl_xor(s2,o); }
    const float mu = s * (1.f/D_MODEL);
    const float rs = rsqrtf(s2*(1.f/D_MODEL) - mu*mu + LN_EPS);
    const float4* wv = (const float4*)lw; const float4* bv = (const float4*)lb;
    float4 w0 = wv[lane*2], w1 = wv[lane*2+1];
    float4 b0 = bv[lane*2], b1 = bv[lane*2+1];
    u32 p0 = (u32)f2bf((v0.x-mu)*rs*w0.x+b0.x) | ((u32)f2bf((v0.y-mu)*rs*w0.y+b0.y)<<16);
    u32 p1 = (u32)f2bf((v0.z-mu)*rs*w0.z+b0.z) | ((u32)f2bf((v0.w-mu)*rs*w0.w+b0.w)<<16);
    u32 p2 = (u32)f2bf((v1.x-mu)*rs*w1.x+b1.x) | ((u32)f2bf((v1.y-mu)*rs*w1.y+b1.y)<<16);
    u32 p3 = (u32)f2bf((v1.z-mu)*rs*w1.z+b1.z) | ((u32)f2bf((v1.w-mu)*rs*w1.w+b1.w)<<16);
    ((uint4*)(xn + (size_t)row * D_MODEL))[lane] = make_uint4(p0,p1,p2,p3);
  } else {
    const int i = (bid - ROWS/4)*256 + threadIdx.x;
    const int NW1 = NCAT*D_MODEL, NW2 = D_MODEL*INNER, STR = 1024*256;
    for (int idx = i; idx < NW1; idx += STR) {
      const int r = idx >> 9, c = idx & 511;
      float v;
      if (r < 2048) v = ipw[idx];
      else {
        const int rr = r - 2048;
        v = (rr & 1) ? dw[(size_t)(rr>>1)*D_MODEL + c]
                     : ipw[(size_t)(2048 + (rr>>1))*D_MODEL + c];
      }
      wcat[idx] = f2bf(v);
    }
    for (int idx = i; idx < NW2; idx += STR) wout[idx] = f2bf(opw[idx]);
    if (i < NCAT) {
      float b;
      if (i < 2048) b = ipb[i];
      else { const int rr = i - 2048; b = (rr & 1) ? db[rr>>1] : ipb[2048 + (rr>>1)]; }
      bcat[i] = b;
    }
  }
}

// ---------------- block swizzle: XCD-chunked + L2-sized (GMxGN) groups ----------------
__device__ __forceinline__ void sched_blk(int nbm, int nbn, int GM, int GN,
                                          int& bM, int& bN) {
  const int nwg = nbm * nbn;
  const int bid = blockIdx.x;
  const int cpx = nwg >> 3;
  const int swz = (bid & 7) * cpx + (bid >> 3);   // contiguous chunk per XCD
  const int gsz = GM * GN;
  const int g   = swz / gsz, loc = swz - g * gsz;
  const int ngn = nbn / GN;
  const int gm  = g / ngn,  gn  = g - gm * ngn;
  bM = gm * GM + (loc % GM);
  bN = gn * GN + (loc / GM);
}

// ================= GEMM1: 256x256 tile, BK=32, 8 waves (2Mx4N, 128x64 each) =====
// r12 measured-best mainloop (frozen): triple-buffered LDS (3x32KB), one
// barrier/iter, counted vmcnt(4), compiler-scheduled lgkm waits. Chunk swizzle
// source-side; B rows N-permuted -> packed stores; d-epilogue fuses scan pass 1.
__global__ __launch_bounds__(512, 2) void gemm1_kernel(const u16* __restrict__ A,
    const u16* __restrict__ Bm, const float* __restrict__ bcat,
    const float* __restrict__ sm, u16* __restrict__ proj, u16* __restrict__ gate,
    u16* __restrict__ dbuf, float* __restrict__ cS) {
  extern __shared__ u16 lds[];                     // 3 x 16384 u16 (A 8192 | B 8192)
  const int tid = threadIdx.x;
  int bM, bN; sched_blk(ROWS/256, NCAT/256, 8, 4, bM, bN);

  const u16* gA0; const u16* gA1; const u16* gB0; const u16* gB1;
  {
    const int p0 = tid,        q0 = p0>>3, t0 = (p0&7) ^ (q0&7);
    const int p1 = 512 + tid,  q1 = p1>>3, t1 = (p1&7) ^ (q1&7);
    const int rA0 = q0*2 + (t0>>2), sA0 = t0&3;
    const int rA1 = q1*2 + (t1>>2), sA1 = t1&3;
    gA0 = A + (size_t)(bM*256 + rA0)*D_MODEL + sA0*8;
    gA1 = A + (size_t)(bM*256 + rA1)*D_MODEL + sA1*8;
    const int c0 = (rA0 & ~63) + ((rA0&15)*4) + ((rA0>>4)&3);
    const int c1 = (rA1 & ~63) + ((rA1&15)*4) + ((rA1>>4)&3);
    gB0 = Bm + (size_t)(bN*256 + c0)*D_MODEL + sA0*8;
    gB1 = Bm + (size_t)(bN*256 + c1)*D_MODEL + sA1*8;
  }

#define STAGE1(KOFF, BUFO) do { \
    glds16(gA0 + (KOFF), lds + (BUFO) + tid*8); \
    glds16(gA1 + (KOFF), lds + (BUFO) + 4096 + tid*8); \
    glds16(gB0 + (KOFF), lds + (BUFO) + 8192 + tid*8); \
    glds16(gB1 + (KOFF), lds + (BUFO) + 12288 + tid*8); } while(0)

  const int lane = tid & 63, wid = tid >> 6;
  const int wm = wid >> 2, wn = wid & 3;          // 2M x 4N waves
  const int rl = lane & 15;
  const int e  = (((lane&1)<<2) + (lane>>4)) ^ (rl>>1);
  const int aoff = wm*4096 + (rl>>1)*64 + e*8;
  const int boff = 8192 + wn*2048 + (rl>>1)*64 + e*8;

  f32x4 acc[8][4];
  #pragma unroll
  for (int m=0;m<8;m++)
    #pragma unroll
    for (int n=0;n<4;n++) acc[m][n] = (f32x4){0.f,0.f,0.f,0.f};

  STAGE1(0, 0);
  STAGE1(32, 16384);
  asm volatile("s_waitcnt vmcnt(4)" ::: "memory");
  __builtin_amdgcn_s_barrier();
  __builtin_amdgcn_sched_barrier(0);

  int cur = 0, stg = 32768;
  for (int kt = 0; kt < 16; ++kt) {
    bf16x8 af[8], bfr[4];
    #pragma unroll
    for (int m=0;m<8;m++) af[m]  = *(const bf16x8*)&lds[cur + aoff + m*512];
    #pragma unroll
    for (int n=0;n<4;n++) bfr[n] = *(const bf16x8*)&lds[cur + boff + n*512];
    if (kt + 2 < 16) STAGE1((kt+2)*32, stg);
    #pragma unroll
    for (int m=0;m<8;m++)
      #pragma unroll
      for (int n=0;n<4;n++)
        acc[m][n] = MFMA16(af[m], bfr[n], acc[m][n]);
    if (kt + 2 < 16) { asm volatile("s_waitcnt vmcnt(4)" ::: "memory"); }
    else             { asm volatile("s_waitcnt vmcnt(0)" ::: "memory"); }
    __builtin_amdgcn_s_barrier();
    __builtin_amdgcn_sched_barrier(0);
    cur += 16384; if (cur == 49152) cur = 0;
    stg += 16384; if (stg == 49152) stg = 0;
  }
#undef STAGE1

  const int colb = bN*256 + wn*64 + rl*4;          // 4 consecutive reordered cols
  const float4 b4 = *(const float4*)&bcat[colb];
  const float* bp = (const float*)&b4;
  if (colb < 2048) {
    u16* outp = (colb < 1024) ? proj : gate;
    const int lcolb = colb & (INNER-1);
    #pragma unroll
    for (int m=0;m<8;m++) {
      const int row0 = bM*256 + wm*128 + m*16 + ((lane>>4)<<2);
      #pragma unroll
      for (int r=0;r<4;r++) {
        float a4[4];
        #pragma unroll
        for (int n=0;n<4;n++) {
          float v = acc[m][n][r] + bp[n];
          a4[n] = (colb < 1024) ? v * sigf(v) : sigf(v);
        }
        u32 lo = (u32)f2bf(a4[0]) | ((u32)f2bf(a4[1])<<16);
        u32 hi = (u32)f2bf(a4[2]) | ((u32)f2bf(a4[3])<<16);
        *(uint2*)&outp[(size_t)(row0+r)*INNER + lcolb] = make_uint2(lo, hi);
      }
    }
  } else {
    const int ch0 = (colb - 2048) >> 1;            // 2 channels per lane
    const int g = lane >> 4;                        // 4-row group within 16-row m-block
    const float A0 = sigf(sm[ch0]), A1 = sigf(sm[ch0+1]);
    const float A0_2 = A0*A0,   A1_2 = A1*A1;
    const float A0_4 = A0_2*A0_2, A1_4 = A1_2*A1_2;
    const float A0_8 = A0_4*A0_4, A1_8 = A1_4*A1_4;
    const float A0_16 = A0_8*A0_8, A1_16 = A1_8*A1_8;
    float S0a = 0.f, S0b = 0.f, S1a = 0.f, S1b = 0.f;   // per-mh running chunk scans
    #pragma unroll
    for (int m=0;m<8;m++) {
      const int row0 = bM*256 + wm*128 + m*16 + (g<<2);
      float sg0 = 0.f, sg1 = 0.f;
      #pragma unroll
      for (int r=0;r<4;r++) {
        const float v0 = acc[m][0][r] + bp[0];     // drive ch0
        const float v1 = acc[m][1][r] + bp[1];     // delta ch0
        const float v2 = acc[m][2][r] + bp[2];     // drive ch0+1
        const float v3 = acc[m][3][r] + bp[3];     // delta ch0+1
        const float d0 = (2.f*sigf(2.f*v0) - 1.f) * fmaxf(sigf(v1), 1e-4f);
        const float d1 = (2.f*sigf(2.f*v2) - 1.f) * fmaxf(sigf(v3), 1e-4f);
        *(u32*)&dbuf[(size_t)(row0+r)*INNER + ch0] = (u32)f2bf(d0) | ((u32)f2bf(d1)<<16);
        sg0 = A0*sg0 + d0;                         // in-thread 4-row decayed scan
        sg1 = A1*sg1 + d1;
      }
      // cross-g combine: s16 = s(g3) + a^4 s(g2) + a^8 s(g1) + a^12 s(g0)
      float p0 = __shfl_xor(sg0, 16), p1 = __shfl_xor(sg1, 16);
      float e0 = (g & 1) ? (sg0 + A0_4*p0) : (p0 + A0_4*sg0);
      float e1 = (g & 1) ? (sg1 + A1_4*p1) : (p1 + A1_4*sg1);
      float q0 = __shfl_xor(e0, 32), q1 = __shfl_xor(e1, 32);
      float s16_0 = (g & 2) ? (e0 + A0_8*q0) : (q0 + A0_8*e0);
      float s16_1 = (g & 2) ? (e1 + A1_8*q1) : (q1 + A1_8*e1);
      if (m < 4) { S0a = A0_16*S0a + s16_0; S1a = A1_16*S1a + s16_1; }
      else       { S0b = A0_16*S0b + s16_0; S1b = A1_16*S1b + s16_1; }
    }
    if (g == 0) {                                  // one writer per (chunk, ch-pair)
      const int b = bM >> 3;
      const int chunk0 = (bM & 7)*4 + wm*2;        // mh=0
      const size_t o0 = ((size_t)b*NCHUNK + chunk0    )*INNER + ch0;
      const size_t o1 = ((size_t)b*NCHUNK + chunk0 + 1)*INNER + ch0;
      *(float2*)&cS[o0] = make_float2(S0a, S1a);
      *(float2*)&cS[o1] = make_float2(S0b, S1b);
    }
  }
}

// ---------------- GEMM2 mainloop (r6 structure, 128x128, triple-buffered) ----------------
__device__ __forceinline__ void gemm_main(const u16* __restrict__ A,
    const u16* __restrict__ Bm, int K, int nkt, int bM, int bN,
    u16* lA, u16* lB, f32x4 acc[4][4]) {
  const int tid = threadIdx.x;
  const int l6  = tid >> 2;
  const int sg  = (tid & 3) ^ (l6 & 3);
  const int pB  = (l6 & 15) * 4 + ((l6 >> 4) & 3);
  const u16* gA = A  + (size_t)(bM*128 + l6)*K + sg*8;
  const u16* gB = Bm + (size_t)(bN*128 + pB)*K + sg*8;
  u16* dA = lA + tid*8;
  u16* dB = lB + tid*8;
  const size_t rstep = (size_t)64*K;

#define STAGE_T(koff, bufo) do { \
    const u16* sA = gA + (koff); const u16* sB = gB + (koff); \
    glds16(sA,         dA + (bufo));        glds16(sA + rstep, dA + (bufo) + 2048); \
    glds16(sB,         dB + (bufo));        glds16(sB + rstep, dB + (bufo) + 2048); \
  } while (0)

  STAGE_T(0, 0);
  STAGE_T(32, 4096);
  asm volatile("s_waitcnt vmcnt(4)" ::: "memory");
  __builtin_amdgcn_s_barrier();
  __builtin_amdgcn_sched_barrier(0);

  const int lane = tid & 63, wv = tid >> 6;
  const int wm = wv >> 1, wn = wv & 1;
  const int kx = ((lane>>4) ^ (lane&3)) * 8;
  const int aoff = (wm*64 + (lane&15))*32 + kx;
  const int boff = (wn*64 + (lane&15))*32 + kx;

  int cur = 0, stg = 8192;
  for (int kt = 0; kt < nkt; ++kt) {
    bf16x8 af[4], bfr[4];
    #pragma unroll
    for (int m=0;m<4;m++) af[m]  = *(const bf16x8*)&lA[cur + aoff + m*512];
    #pragma unroll
    for (int n=0;n<4;n++) bfr[n] = *(const bf16x8*)&lB[cur + boff + n*512];
    if (kt + 2 < nkt) STAGE_T((kt+2)*32, stg);
    #pragma unroll
    for (int m=0;m<4;m++)
      #pragma unroll
      for (int n=0;n<4;n++)
        acc[m][n] = MFMA16(af[m], bfr[n], acc[m][n]);
    if (kt + 2 < nkt) { asm volatile("s_waitcnt vmcnt(4)" ::: "memory"); }
    else              { asm volatile("s_waitcnt vmcnt(0)" ::: "memory"); }
    __builtin_amdgcn_s_barrier();
    __builtin_amdgcn_sched_barrier(0);
    cur += 4096; if (cur == 12288) cur = 0;
    stg += 4096; if (stg == 12288) stg = 0;
  }
#undef STAGE_T
}

// ---------------- GEMM2: z @ out_proj_w^T + bias + residual (fp32 out) ----------------
__global__ __launch_bounds__(256, 3) void gemm2_kernel(const u16* __restrict__ A,
    const u16* __restrict__ Bm, const float* __restrict__ ob,
    const float* __restrict__ resid, float* __restrict__ out) {
  __shared__ u16 lA[12288], lB[12288];
  f32x4 acc[4][4];
  #pragma unroll
  for (int m=0;m<4;m++)
    #pragma unroll
    for (int n=0;n<4;n++) acc[m][n] = (f32x4){0.f,0.f,0.f,0.f};
  int bM, bN; sched_blk(ROWS/128, D_MODEL/128, 8, 4, bM, bN);
  gemm_main(A, Bm, INNER, INNER/32, bM, bN, lA, lB, acc);
  const int lane = threadIdx.x & 63, wv = threadIdx.x >> 6;
  const int wm = wv>>1, wn = wv&1;
  const int colb = bN*128 + wn*64 + (lane&15)*4;
  const float4 ob4 = *(const float4*)&ob[colb];
  #pragma unroll
  for (int m=0;m<4;m++) {
    const int row0 = bM*128 + wm*64 + m*16 + ((lane>>4)<<2);
    #pragma unroll
    for (int r=0;r<4;r++) {
      const size_t idx = (size_t)(row0+r)*D_MODEL + colb;
      float4 rs = *(const float4*)&resid[idx];
      float4 o;
      o.x = acc[m][0][r] + ob4.x + rs.x;
      o.y = acc[m][1][r] + ob4.y + rs.y;
      o.z = acc[m][2][r] + ob4.z + rs.z;
      o.w = acc[m][3][r] + ob4.w + rs.w;
      *(float4*)&out[idx] = o;
    }
  }
}

// ------- scan pass 3 (+inline carry combine): scan + causal conv + gating -> z --------
__global__ __launch_bounds__(256) void scan3_kernel(const u16* __restrict__ proj,
    const u16* __restrict__ gate, const u16* __restrict__ d,
    const float* __restrict__ cS, const float* __restrict__ sm,
    const float* __restrict__ cw, const float* __restrict__ cb,
    const float* __restrict__ sk, u16* __restrict__ z) {
  const int blk = blockIdx.x;
  const int half = blk & 1, ch = (blk>>1) & (NCHUNK-1), b = blk >> 6;
  const int c0 = half*512 + threadIdx.x*2;
  const float a0 = sigf(sm[c0]), a1 = sigf(sm[c0+1]);
  const float cb0 = cb[c0], cb1 = cb[c0+1];
  const float sk0 = sk[c0], sk1 = sk[c0+1];
  const float w00=cw[c0*4+0], w01=cw[c0*4+1], w02=cw[c0*4+2], w03=cw[c0*4+3];
  const float w10=cw[c0*4+4], w11=cw[c0*4+5], w12=cw[c0*4+6], w13=cw[c0*4+7];
  // ---- inline scan2: exclusive carry over previous chunks (cS is 1MB, L2-hot) ----
  float A0 = a0, A1 = a1;
  #pragma unroll
  for (int i=0;i<6;i++){ A0*=A0; A1*=A1; }           // a^64 = a^CHUNK
  float s0 = 0.f, s1 = 0.f;
  for (int j = 0; j < ch; ++j) {
    const size_t oj = ((size_t)b*NCHUNK + j)*INNER + c0;
    const float2 cv = *(const float2*)&cS[oj];
    s0 = A0*s0 + cv.x;
    s1 = A1*s1 + cv.y;
  }
  const int t0 = ch*CHUNK;
  const size_t rowb = (size_t)b*SEQ*INNER + c0;
  float pa0=0,pb0=0,pc0=0, pa1=0,pb1=0,pc1=0;
  if (ch > 0) {
    u32 u3 = *(const u32*)(proj + rowb + (size_t)(t0-3)*INNER);
    u32 u2 = *(const u32*)(proj + rowb + (size_t)(t0-2)*INNER);
    u32 u1 = *(const u32*)(proj + rowb + (size_t)(t0-1)*INNER);
    pa0 = bf2f(u3&0xffffu); pa1 = bf2f(u3>>16);
    pb0 = bf2f(u2&0xffffu); pb1 = bf2f(u2>>16);
    pc0 = bf2f(u1&0xffffu); pc1 = bf2f(u1>>16);
  }
  size_t base = rowb + (size_t)t0*INNER;
  for (int t=0;t<CHUNK;t++) {
    u32 pu = *(const u32*)(proj + base);
    const float pd0 = bf2f(pu&0xffffu), pd1 = bf2f(pu>>16);
    const float co0 = w00*pa0 + w01*pb0 + w02*pc0 + w03*pd0 + cb0;
    const float co1 = w10*pa1 + w11*pb1 + w12*pc1 + w13*pd1 + cb1;
    pa0=pb0; pb0=pc0; pc0=pd0;  pa1=pb1; pb1=pc1; pc1=pd1;
    u32 du = *(const u32*)(d + base);
    s0 = a0*s0 + bf2f(du&0xffffu);
    s1 = a1*s1 + bf2f(du>>16);
    u32 gu = *(const u32*)(gate + base);
    const float z0 = (s0 + sk0*co0)*bf2f(gu&0xffffu);
    const float z1 = (s1 + sk1*co1)*bf2f(gu>>16);
    *(u32*)(z + base) = (u32)f2bf(z0) | ((u32)f2bf(z1)<<16);
    base += INNER;
  }
}

extern "C" void kernel_launch(void* const* d_in, const int* in_sizes, int n_in,
                              void* d_out, int out_size, void* d_ws, size_t ws_size,
                              hipStream_t stream) {
  const float* x    = (const float*)d_in[0];
  const float* ln_w = (const float*)d_in[1];
  const float* ln_b = (const float*)d_in[2];
  const float* ipw  = (const float*)d_in[3];
  const float* ipb  = (const float*)d_in[4];
  const float* cw   = (const float*)d_in[5];
  const float* cb   = (const float*)d_in[6];
  const float* dw   = (const float*)d_in[7];
  const float* db   = (const float*)d_in[8];
  const float* sm   = (const float*)d_in[9];
  const float* sk   = (const float*)d_in[10];
  const float* opw  = (const float*)d_in[11];
  const float* opb  = (const float*)d_in[12];
  float* out = (float*)d_out;

  uint8_t* w = (uint8_t*)d_ws;
  u16* xn    = (u16*)w;  w += (size_t)ROWS*D_MODEL*2;
  u16* wcat  = (u16*)w;  w += (size_t)NCAT*D_MODEL*2;
  u16* wout  = (u16*)w;  w += (size_t)D_MODEL*INNER*2;
  u16* proj  = (u16*)w;  w += (size_t)ROWS*INNER*2;
  u16* gate  = (u16*)w;  w += (size_t)ROWS*INNER*2;
  u16* dbuf  = (u16*)w;  w += (size_t)ROWS*INNER*2;
  u16* z     = (u16*)w;  w += (size_t)ROWS*INNER*2;
  float* cS    = (float*)w; w += (size_t)BATCH*NCHUNK*INNER*4;
  float* bcat  = (float*)w; w += (size_t)NCAT*4;

  prep_kernel<<<ROWS/4 + 1024, 256, 0, stream>>>(x, ln_w, ln_b, ipw, dw, opw, ipb, db,
                                                 xn, wcat, wout, bcat);
  gemm1_kernel<<<(ROWS/256)*(NCAT/256), 512, 98304, stream>>>(xn, wcat, bcat, sm, proj, gate, dbuf, cS);
  scan3_kernel<<<BATCH*NCHUNK*2, 256, 0, stream>>>(proj, gate, dbuf, cS, sm, cw, cb, sk, z);
  gemm2_kernel<<<(ROWS/128)*(D_MODEL/128), 256, 0, stream>>>(z, wout, opb, x, out);
}